// Round 1
// baseline (1853.924 us; speedup 1.0000x reference)
//
#include <hip/hip_runtime.h>

#define NPTS 32768
#define DIM 32
#define NH 8
#define NC 3
#define BSZ 128
#define NB 256
#define DH 35
#define DP 36
#define NSEG 24   // C*H

typedef unsigned long long ull;

__device__ __forceinline__ unsigned fmap(float f){
  unsigned b = __float_as_uint(f);
  return (b & 0x80000000u) ? ~b : (b | 0x80000000u);
}
__device__ __forceinline__ float funmap(unsigned u){
  unsigned b = (u & 0x80000000u) ? (u & 0x7fffffffu) : ~u;
  return __uint_as_float(b);
}

// ---------------- prep: qw_sqrt[h][r] = sqrt(2*sum_k exp(min(sum_d w,50))) + slot init
__global__ __launch_bounds__(256) void k_prep(const float* __restrict__ w_rpe,
        float* __restrict__ qw_sqrt, unsigned* __restrict__ slots_hi,
        unsigned* __restrict__ slots_lo){
  int tid = threadIdx.x;
  if (tid < NSEG){ slots_hi[tid] = 0u; slots_lo[tid] = 0xFFFFFFFFu; }
  __shared__ float S[24][8];
  if (tid < 192){
    int hr = tid >> 3, kk = tid & 7;
    int h = hr / 3, r = hr % 3;
    float s = 0.f;
    #pragma unroll
    for (int d = 0; d < DIM; ++d) s += w_rpe[(h*DIM + d)*24 + (r*8 + kk)];
    S[hr][kk] = expf(fminf(s, 50.f));
  }
  __syncthreads();
  if (tid < 24){
    float q = 0.f;
    #pragma unroll
    for (int kk = 0; kk < 8; ++kk) q += S[tid][kk];
    qw_sqrt[tid] = sqrtf(2.f * q);
  }
}

// ---------------- LayerNorm1
__global__ __launch_bounds__(256) void k_ln(const float* __restrict__ x,
        const float* __restrict__ w, const float* __restrict__ b,
        float* __restrict__ xn){
  int n = blockIdx.x*256 + threadIdx.x;
  if (n >= NPTS) return;
  const float4* xr = (const float4*)(x + (size_t)n*DIM);
  float4 v[8];
  float s = 0.f;
  #pragma unroll
  for (int u = 0; u < 8; ++u){ v[u] = xr[u]; s += v[u].x+v[u].y+v[u].z+v[u].w; }
  float mu = s * (1.f/32.f);
  float var = 0.f;
  #pragma unroll
  for (int u = 0; u < 8; ++u){
    float a0=v[u].x-mu, a1=v[u].y-mu, a2=v[u].z-mu, a3=v[u].w-mu;
    var += a0*a0+a1*a1+a2*a2+a3*a3;
  }
  var *= (1.f/32.f);
  float rs = rsqrtf(var + 1e-5f);
  const float4* w4 = (const float4*)w;
  const float4* b4 = (const float4*)b;
  float4* o = (float4*)(xn + (size_t)n*DIM);
  #pragma unroll
  for (int u = 0; u < 8; ++u){
    float4 ww = w4[u], bb = b4[u], r;
    r.x = (v[u].x-mu)*rs*ww.x + bb.x;
    r.y = (v[u].y-mu)*rs*ww.y + bb.y;
    r.z = (v[u].z-mu)*rs*ww.z + bb.z;
    r.w = (v[u].w-mu)*rs*ww.w + bb.w;
    o[u] = r;
  }
}

// ---------------- QKV projection + q_hat/k_hat assembly
__global__ __launch_bounds__(256) void k_qkv(const float* __restrict__ xn,
        const float* __restrict__ coords, const float* __restrict__ wq,
        const float* __restrict__ wk, const float* __restrict__ wv,
        const float* __restrict__ qw_sqrt,
        float* __restrict__ q_hat, float* __restrict__ k_hat,
        float* __restrict__ val){
  __shared__ float W[3][DIM][NH*DIM];   // 96 KB
  __shared__ float XT[32][33];
  int tid = threadIdx.x;
  for (int idx = tid; idx < 3*DIM*NH*DIM; idx += 256){
    int which = idx / (DIM*NH*DIM);
    int rem = idx % (DIM*NH*DIM);
    const float* src = which==0 ? wq : (which==1 ? wk : wv);
    W[which][rem/(NH*DIM)][rem%(NH*DIM)] = src[rem];
  }
  int base = blockIdx.x * 32;
  for (int idx = tid; idx < 32*DIM; idx += 256)
    XT[idx/32][idx%32] = xn[(size_t)(base + idx/32)*DIM + (idx%32)];
  __syncthreads();
  int h = tid >> 5, i = tid & 31;
  int n = base + i;
  float xr[32];
  #pragma unroll
  for (int d = 0; d < 32; ++d) xr[d] = XT[i][d];
  float cpart[3];
  #pragma unroll
  for (int r = 0; r < 3; ++r) cpart[r] = qw_sqrt[h*3+r] * coords[(size_t)n*3 + r];

  float* dq = q_hat + ((size_t)h*NPTS + n)*DP;
  float* dk = k_hat + ((size_t)h*NPTS + n)*DP;
  float* dv = val   + ((size_t)h*NPTS + n)*DIM;
  #pragma unroll
  for (int which = 0; which < 3; ++which){
    for (int j0 = 0; j0 < 32; j0 += 4){
      float4 acc = {0.f,0.f,0.f,0.f};
      #pragma unroll
      for (int d = 0; d < 32; ++d){
        float4 wv4 = *(const float4*)&W[which][d][h*32 + j0];
        acc.x += xr[d]*wv4.x; acc.y += xr[d]*wv4.y;
        acc.z += xr[d]*wv4.z; acc.w += xr[d]*wv4.w;
      }
      if (which == 0)      *(float4*)&dq[j0] = acc;
      else if (which == 1) *(float4*)&dk[j0] = acc;
      else                 *(float4*)&dv[j0] = acc;
    }
  }
  dq[32]=cpart[0]; dq[33]=cpart[1]; dq[34]=cpart[2]; dq[35]=0.f;
  dk[32]=cpart[0]; dk[33]=cpart[1]; dk[34]=cpart[2]; dk[35]=0.f;
}

// ---------------- LSH hash values + per-(c,h) hi/lo
__global__ __launch_bounds__(256) void k_hash(const float* __restrict__ q_hat,
        const float* __restrict__ k_hat, const float* __restrict__ alpha,
        float* __restrict__ qh_buf, float* __restrict__ kh_buf,
        unsigned* __restrict__ slots_hi, unsigned* __restrict__ slots_lo){
  int h = blockIdx.y;
  int n = blockIdx.x*256 + threadIdx.x;
  __shared__ float A[DH][NC];
  for (int idx = threadIdx.x; idx < DH*NC; idx += 256)
    A[idx/3][idx%3] = alpha[h*DH*NC + idx];
  __syncthreads();
  float qr[DH], kr[DH];
  const float* qp = q_hat + ((size_t)h*NPTS + n)*DP;
  const float* kp = k_hat + ((size_t)h*NPTS + n)*DP;
  #pragma unroll
  for (int d = 0; d < DH; ++d){ qr[d] = qp[d]; kr[d] = kp[d]; }
  #pragma unroll
  for (int c = 0; c < NC; ++c){
    float qh = 0.f, kh = 0.f;
    #pragma unroll
    for (int d = 0; d < DH; ++d){ qh += qr[d]*A[d][c]; kh += kr[d]*A[d][c]; }
    qh_buf[((size_t)(c*NH + h))*NPTS + n] = qh;
    kh_buf[((size_t)(c*NH + h))*NPTS + n] = kh;
    float hi = fmaxf(qh, kh), lo = fminf(qh, kh);
    #pragma unroll
    for (int off = 32; off; off >>= 1){
      hi = fmaxf(hi, __shfl_xor(hi, off));
      lo = fminf(lo, __shfl_xor(lo, off));
    }
    if ((threadIdx.x & 63) == 0){
      atomicMax(&slots_hi[c*NH + h], fmap(hi));
      atomicMin(&slots_lo[c*NH + h], fmap(lo));
    }
  }
}

// ---------------- build packed sort keys
__global__ __launch_bounds__(256) void k_pack(const float* __restrict__ qh_buf,
        const float* __restrict__ kh_buf, const int* __restrict__ shifts,
        const unsigned* __restrict__ slots_hi, const unsigned* __restrict__ slots_lo,
        ull* __restrict__ packed){
  int seg = blockIdx.y;
  int n = blockIdx.x*256 + threadIdx.x;
  float hs = funmap(slots_hi[seg]) - funmap(slots_lo[seg]);
  size_t idx = (size_t)seg*NPTS + n;
  float sh = (float)shifts[idx] * hs;
  float kq = qh_buf[idx] + sh;
  float kk = kh_buf[idx] + sh;
  packed[(size_t)seg*NPTS + n]          = ((ull)fmap(kq) << 32) | (unsigned)n;
  packed[(size_t)(NSEG + seg)*NPTS + n] = ((ull)fmap(kk) << 32) | (unsigned)n;
}

// ---------------- bitonic sort: LDS chunk kernel (8192 elems, phases k_lo..k_hi, j<=4096)
__global__ __launch_bounds__(1024) void k_sort_local(ull* __restrict__ data,
        unsigned k_lo, unsigned k_hi){
  __shared__ ull ld[8192];     // 64 KB
  int chunk = blockIdx.x;
  size_t base = (size_t)chunk * 8192;
  unsigned segoff = (unsigned)(chunk & 3) * 8192u;  // index within 32768-segment
  for (int idx = threadIdx.x; idx < 8192; idx += 1024) ld[idx] = data[base + idx];
  __syncthreads();
  for (unsigned k = k_lo; k <= k_hi; k <<= 1){
    unsigned j0 = (k >> 1) < 4096u ? (k >> 1) : 4096u;
    for (unsigned j = j0; j > 0; j >>= 1){
      for (unsigned p = threadIdx.x; p < 4096; p += 1024){
        unsigned i  = ((p & ~(j-1)) << 1) | (p & (j-1));
        unsigned x2 = i | j;
        bool up = (((segoff + i) & k) == 0);
        ull a = ld[i], b = ld[x2];
        if ((a > b) == up){ ld[i] = b; ld[x2] = a; }
      }
      __syncthreads();
    }
  }
  for (int idx = threadIdx.x; idx < 8192; idx += 1024) data[base + idx] = ld[idx];
}

// ---------------- bitonic sort: one global compare-exchange pass
__global__ __launch_bounds__(256) void k_sort_global(ull* __restrict__ data,
        unsigned k, unsigned j){
  unsigned t = blockIdx.x*256 + threadIdx.x;       // 48*16384 total
  unsigned seg = t >> 14;
  unsigned p = t & 16383u;
  unsigned i  = ((p & ~(j-1)) << 1) | (p & (j-1));
  unsigned x2 = i | j;
  size_t base = (size_t)seg << 15;
  bool up = ((i & k) == 0);
  ull a = data[base + i], b = data[base + x2];
  if ((a > b) == up){ data[base + i] = b; data[base + x2] = a; }
}

// ---------------- bucketed kernelized attention
__global__ __launch_bounds__(128) void k_attn(const float* __restrict__ q_hat,
        const float* __restrict__ k_hat, const float* __restrict__ val,
        const ull* __restrict__ packed, float* __restrict__ o_acc,
        float* __restrict__ logit_acc){
  int blk = blockIdx.x;
  int seg = blk >> 8;       // /NB
  int b = blk & 255;
  int h = seg & 7;
  int t = threadIdx.x;
  __shared__ float Ks[BSZ][DP];
  __shared__ float Vs[BSZ][DIM];
  const ull* pq = packed + ((size_t)seg << 15) + (size_t)b*BSZ;
  const ull* pk = packed + ((size_t)(NSEG + seg) << 15) + (size_t)b*BSZ;
  unsigned iq = (unsigned)(pq[t] & 0xffffffffull);
  unsigned ik = (unsigned)(pk[t] & 0xffffffffull);
  float4 qv[9];
  const float4* qr = (const float4*)(q_hat + ((size_t)h*NPTS + iq)*DP);
  #pragma unroll
  for (int u = 0; u < 9; ++u) qv[u] = qr[u];
  const float4* krow = (const float4*)(k_hat + ((size_t)h*NPTS + ik)*DP);
  #pragma unroll
  for (int u = 0; u < 9; ++u) ((float4*)&Ks[t][0])[u] = krow[u];
  const float4* vrow = (const float4*)(val + ((size_t)h*NPTS + ik)*DIM);
  #pragma unroll
  for (int u = 0; u < 8; ++u) ((float4*)&Vs[t][0])[u] = vrow[u];
  __syncthreads();

  float o[32];
  #pragma unroll
  for (int d = 0; d < 32; ++d) o[d] = 0.f;
  float den = 0.f;
  for (int j = 0; j < BSZ; ++j){
    float dist = 0.f;
    const float4* kk = (const float4*)&Ks[j][0];
    #pragma unroll
    for (int u = 0; u < 9; ++u){
      float4 kv = kk[u];
      float d0 = qv[u].x - kv.x; dist += d0*d0;
      float d1 = qv[u].y - kv.y; dist += d1*d1;
      float d2 = qv[u].z - kv.z; dist += d2*d2;
      float d3 = qv[u].w - kv.w; dist += d3*d3;
    }
    float wgt = __expf(-0.5f * dist);
    den += wgt;
    const float4* vv = (const float4*)&Vs[j][0];
    #pragma unroll
    for (int u = 0; u < 8; ++u){
      float4 v4 = vv[u];
      o[u*4+0] += wgt*v4.x; o[u*4+1] += wgt*v4.y;
      o[u*4+2] += wgt*v4.z; o[u*4+3] += wgt*v4.w;
    }
  }
  float* dst = o_acc + ((size_t)h*NPTS + iq)*DIM;
  #pragma unroll
  for (int d = 0; d < 32; ++d) atomicAdd(&dst[d], o[d]);
  atomicAdd(&logit_acc[(size_t)h*NPTS + iq], den + 1e-20f);
}

// ---------------- out-proj + residual + LN2 + FF + residual
__global__ __launch_bounds__(256) void k_final(const float* __restrict__ x,
        const float* __restrict__ o_acc, const float* __restrict__ logit_acc,
        const float* __restrict__ out_w, const float* __restrict__ out_b,
        const float* __restrict__ n2w, const float* __restrict__ n2b,
        const float* __restrict__ f1w, const float* __restrict__ f1b,
        const float* __restrict__ f2w, const float* __restrict__ f2b,
        float* __restrict__ out){
  __shared__ float OW[256][32];   // 32 KB
  __shared__ float F1[32][32];
  __shared__ float F2[32][32];
  int tid = threadIdx.x;
  for (int idx = tid; idx < 256*32; idx += 256) OW[idx/32][idx%32] = out_w[idx];
  for (int idx = tid; idx < 1024; idx += 256){
    F1[idx/32][idx%32] = f1w[idx];
    F2[idx/32][idx%32] = f2w[idx];
  }
  __syncthreads();
  int n = blockIdx.x*256 + tid;
  float attn[32];
  #pragma unroll
  for (int j = 0; j < 32; ++j) attn[j] = out_b[j];
  for (int h = 0; h < 8; ++h){
    float inv = 1.f / logit_acc[(size_t)h*NPTS + n];
    const float4* orow = (const float4*)(o_acc + ((size_t)h*NPTS + n)*DIM);
    #pragma unroll
    for (int u = 0; u < 8; ++u){
      float4 ov = orow[u];
      float vals[4] = {ov.x*inv, ov.y*inv, ov.z*inv, ov.w*inv};
      #pragma unroll
      for (int s = 0; s < 4; ++s){
        const float* wrow = &OW[h*32 + u*4 + s][0];
        #pragma unroll
        for (int j = 0; j < 32; ++j) attn[j] += vals[s] * wrow[j];
      }
    }
  }
  const float* xp = x + (size_t)n*DIM;
  float xr[32]; float s = 0.f;
  #pragma unroll
  for (int d = 0; d < 32; ++d){ xr[d] = xp[d] + attn[d]; s += xr[d]; }
  float mu = s * (1.f/32.f);
  float var = 0.f;
  #pragma unroll
  for (int d = 0; d < 32; ++d){ float dx = xr[d]-mu; var += dx*dx; }
  var *= (1.f/32.f);
  float rs = rsqrtf(var + 1e-5f);
  float xn2[32];
  #pragma unroll
  for (int d = 0; d < 32; ++d) xn2[d] = (xr[d]-mu)*rs*n2w[d] + n2b[d];
  float z[32];
  #pragma unroll
  for (int j = 0; j < 32; ++j) z[j] = f1b[j];
  #pragma unroll
  for (int d = 0; d < 32; ++d){
    float xd = xn2[d];
    const float* wrow = &F1[d][0];
    #pragma unroll
    for (int j = 0; j < 32; ++j) z[j] += xd * wrow[j];
  }
  #pragma unroll
  for (int j = 0; j < 32; ++j) z[j] = z[j] / (1.f + __expf(-z[j]));
  float y[32];
  #pragma unroll
  for (int d = 0; d < 32; ++d) y[d] = f2b[d];
  #pragma unroll
  for (int j = 0; j < 32; ++j){
    float zj = z[j];
    const float* wrow = &F2[j][0];
    #pragma unroll
    for (int d = 0; d < 32; ++d) y[d] += zj * wrow[d];
  }
  float* op = out + (size_t)n*DIM;
  #pragma unroll
  for (int d = 0; d < 32; ++d) op[d] = xr[d] + y[d];
}

extern "C" void kernel_launch(void* const* d_in, const int* in_sizes, int n_in,
                              void* d_out, int out_size, void* d_ws, size_t ws_size,
                              hipStream_t stream){
  const float* x      = (const float*)d_in[0];
  const float* coords = (const float*)d_in[1];
  const int*   shifts = (const int*)d_in[2];
  const float* n1w    = (const float*)d_in[3];
  const float* n1b    = (const float*)d_in[4];
  const float* wq     = (const float*)d_in[5];
  const float* wk     = (const float*)d_in[6];
  const float* wv     = (const float*)d_in[7];
  const float* w_rpe  = (const float*)d_in[8];
  const float* alpha  = (const float*)d_in[9];
  const float* out_w  = (const float*)d_in[10];
  const float* out_b  = (const float*)d_in[11];
  const float* n2w    = (const float*)d_in[12];
  const float* n2b    = (const float*)d_in[13];
  const float* f1w    = (const float*)d_in[14];
  const float* f1b    = (const float*)d_in[15];
  const float* f2w    = (const float*)d_in[16];
  const float* f2b    = (const float*)d_in[17];
  float* out = (float*)d_out;

  char* ws = (char*)d_ws;
  size_t off = 0;
  auto alloc = [&](size_t bytes){ size_t o = off; off += (bytes + 255) & ~(size_t)255; return o; };
  float*    qw_sqrt   = (float*)   (ws + alloc(24*4));
  unsigned* slots_hi  = (unsigned*)(ws + alloc(24*4));
  unsigned* slots_lo  = (unsigned*)(ws + alloc(24*4));
  float*    xn        = (float*)   (ws + alloc((size_t)NPTS*DIM*4));
  float*    q_hat     = (float*)   (ws + alloc((size_t)NH*NPTS*DP*4));
  float*    k_hat     = (float*)   (ws + alloc((size_t)NH*NPTS*DP*4));
  float*    val       = (float*)   (ws + alloc((size_t)NH*NPTS*DIM*4));
  float*    qh_buf    = (float*)   (ws + alloc((size_t)NSEG*NPTS*4));
  float*    kh_buf    = (float*)   (ws + alloc((size_t)NSEG*NPTS*4));
  ull*      packed    = (ull*)     (ws + alloc((size_t)2*NSEG*NPTS*8));
  float*    o_acc     = (float*)   (ws + alloc((size_t)NH*NPTS*DIM*4));
  float*    logit_acc = (float*)   (ws + alloc((size_t)NH*NPTS*4));
  if (off > ws_size) return;   // workspace too small -> leave output poisoned

  hipMemsetAsync(o_acc, 0, (size_t)NH*NPTS*DIM*4, stream);
  hipMemsetAsync(logit_acc, 0, (size_t)NH*NPTS*4, stream);

  k_prep<<<1, 256, 0, stream>>>(w_rpe, qw_sqrt, slots_hi, slots_lo);
  k_ln<<<NPTS/256, 256, 0, stream>>>(x, n1w, n1b, xn);
  k_qkv<<<NPTS/32, 256, 0, stream>>>(xn, coords, wq, wk, wv, qw_sqrt, q_hat, k_hat, val);
  k_hash<<<dim3(NPTS/256, NH), 256, 0, stream>>>(q_hat, k_hat, alpha, qh_buf, kh_buf,
                                                 slots_hi, slots_lo);
  k_pack<<<dim3(NPTS/256, NSEG), 256, 0, stream>>>(qh_buf, kh_buf, shifts,
                                                   slots_hi, slots_lo, packed);
  // 48 segments of 32768 -> bitonic
  k_sort_local<<<2*NSEG*4, 1024, 0, stream>>>(packed, 2u, 8192u);
  k_sort_global<<<(2*NSEG*16384)/256, 256, 0, stream>>>(packed, 16384u, 8192u);
  k_sort_local<<<2*NSEG*4, 1024, 0, stream>>>(packed, 16384u, 16384u);
  k_sort_global<<<(2*NSEG*16384)/256, 256, 0, stream>>>(packed, 32768u, 16384u);
  k_sort_global<<<(2*NSEG*16384)/256, 256, 0, stream>>>(packed, 32768u, 8192u);
  k_sort_local<<<2*NSEG*4, 1024, 0, stream>>>(packed, 32768u, 32768u);

  k_attn<<<NSEG*NB, 128, 0, stream>>>(q_hat, k_hat, val, packed, o_acc, logit_acc);
  k_final<<<NPTS/256, 256, 0, stream>>>(x, o_acc, logit_acc, out_w, out_b,
                                        n2w, n2b, f1w, f1b, f2w, f2b, out);
}

// Round 2
// 620.816 us; speedup vs baseline: 2.9863x; 2.9863x over previous
//
#include <hip/hip_runtime.h>

#define NPTS 32768
#define DIM 32
#define NH 8
#define NC 3
#define BSZ 128
#define NB 256
#define DH 35
#define DP 36
#define NSEG 24   // C*H

typedef unsigned long long ull;
typedef __attribute__((ext_vector_type(8))) short bf16x8;
typedef __attribute__((ext_vector_type(4))) float f32x4;

__device__ __forceinline__ unsigned fmap(float f){
  unsigned b = __float_as_uint(f);
  return (b & 0x80000000u) ? ~b : (b | 0x80000000u);
}
__device__ __forceinline__ float funmap(unsigned u){
  unsigned b = (u & 0x80000000u) ? (u & 0x7fffffffu) : ~u;
  return __uint_as_float(b);
}
__device__ __forceinline__ unsigned short f2bf(float f){
  unsigned u = __float_as_uint(f);
  u += 0x7fffu + ((u >> 16) & 1u);
  return (unsigned short)(u >> 16);
}
__device__ __forceinline__ float bf2f(unsigned short h){
  return __uint_as_float(((unsigned)h) << 16);
}
__device__ __forceinline__ void cvt8(const float* f, bf16x8& hi, bf16x8& lo){
  #pragma unroll
  for (int j = 0; j < 8; ++j){
    unsigned short hb = f2bf(f[j]);
    hi[j] = (short)hb;
    lo[j] = (short)f2bf(f[j] - bf2f(hb));
  }
}

// ---------------- prep: qw_sqrt[h][r] = sqrt(2*sum_k exp(min(sum_d w,50))) + slot init
__global__ __launch_bounds__(256) void k_prep(const float* __restrict__ w_rpe,
        float* __restrict__ qw_sqrt, unsigned* __restrict__ slots_hi,
        unsigned* __restrict__ slots_lo){
  int tid = threadIdx.x;
  if (tid < NSEG){ slots_hi[tid] = 0u; slots_lo[tid] = 0xFFFFFFFFu; }
  __shared__ float S[24][8];
  if (tid < 192){
    int hr = tid >> 3, kk = tid & 7;
    int h = hr / 3, r = hr % 3;
    float s = 0.f;
    #pragma unroll
    for (int d = 0; d < DIM; ++d) s += w_rpe[(h*DIM + d)*24 + (r*8 + kk)];
    S[hr][kk] = expf(fminf(s, 50.f));
  }
  __syncthreads();
  if (tid < 24){
    float q = 0.f;
    #pragma unroll
    for (int kk = 0; kk < 8; ++kk) q += S[tid][kk];
    qw_sqrt[tid] = sqrtf(2.f * q);
  }
}

// ---------------- LayerNorm1
__global__ __launch_bounds__(256) void k_ln(const float* __restrict__ x,
        const float* __restrict__ w, const float* __restrict__ b,
        float* __restrict__ xn){
  int n = blockIdx.x*256 + threadIdx.x;
  if (n >= NPTS) return;
  const float4* xr = (const float4*)(x + (size_t)n*DIM);
  float4 v[8];
  float s = 0.f;
  #pragma unroll
  for (int u = 0; u < 8; ++u){ v[u] = xr[u]; s += v[u].x+v[u].y+v[u].z+v[u].w; }
  float mu = s * (1.f/32.f);
  float var = 0.f;
  #pragma unroll
  for (int u = 0; u < 8; ++u){
    float a0=v[u].x-mu, a1=v[u].y-mu, a2=v[u].z-mu, a3=v[u].w-mu;
    var += a0*a0+a1*a1+a2*a2+a3*a3;
  }
  var *= (1.f/32.f);
  float rs = rsqrtf(var + 1e-5f);
  const float4* w4 = (const float4*)w;
  const float4* b4 = (const float4*)b;
  float4* o = (float4*)(xn + (size_t)n*DIM);
  #pragma unroll
  for (int u = 0; u < 8; ++u){
    float4 ww = w4[u], bb = b4[u], r;
    r.x = (v[u].x-mu)*rs*ww.x + bb.x;
    r.y = (v[u].y-mu)*rs*ww.y + bb.y;
    r.z = (v[u].z-mu)*rs*ww.z + bb.z;
    r.w = (v[u].w-mu)*rs*ww.w + bb.w;
    o[u] = r;
  }
}

// ---------------- QKV projection + q_hat/k_hat assembly
__global__ __launch_bounds__(256) void k_qkv(const float* __restrict__ xn,
        const float* __restrict__ coords, const float* __restrict__ wq,
        const float* __restrict__ wk, const float* __restrict__ wv,
        const float* __restrict__ qw_sqrt,
        float* __restrict__ q_hat, float* __restrict__ k_hat,
        float* __restrict__ val){
  __shared__ float W[3][DIM][NH*DIM];   // 96 KB
  __shared__ float XT[32][33];
  int tid = threadIdx.x;
  for (int idx = tid; idx < 3*DIM*NH*DIM; idx += 256){
    int which = idx / (DIM*NH*DIM);
    int rem = idx % (DIM*NH*DIM);
    const float* src = which==0 ? wq : (which==1 ? wk : wv);
    W[which][rem/(NH*DIM)][rem%(NH*DIM)] = src[rem];
  }
  int base = blockIdx.x * 32;
  for (int idx = tid; idx < 32*DIM; idx += 256)
    XT[idx/32][idx%32] = xn[(size_t)(base + idx/32)*DIM + (idx%32)];
  __syncthreads();
  int h = tid >> 5, i = tid & 31;
  int n = base + i;
  float xr[32];
  #pragma unroll
  for (int d = 0; d < 32; ++d) xr[d] = XT[i][d];
  float cpart[3];
  #pragma unroll
  for (int r = 0; r < 3; ++r) cpart[r] = qw_sqrt[h*3+r] * coords[(size_t)n*3 + r];

  float* dq = q_hat + ((size_t)h*NPTS + n)*DP;
  float* dk = k_hat + ((size_t)h*NPTS + n)*DP;
  float* dv = val   + ((size_t)h*NPTS + n)*DIM;
  #pragma unroll
  for (int which = 0; which < 3; ++which){
    for (int j0 = 0; j0 < 32; j0 += 4){
      float4 acc = {0.f,0.f,0.f,0.f};
      #pragma unroll
      for (int d = 0; d < 32; ++d){
        float4 wv4 = *(const float4*)&W[which][d][h*32 + j0];
        acc.x += xr[d]*wv4.x; acc.y += xr[d]*wv4.y;
        acc.z += xr[d]*wv4.z; acc.w += xr[d]*wv4.w;
      }
      if (which == 0)      *(float4*)&dq[j0] = acc;
      else if (which == 1) *(float4*)&dk[j0] = acc;
      else                 *(float4*)&dv[j0] = acc;
    }
  }
  dq[32]=cpart[0]; dq[33]=cpart[1]; dq[34]=cpart[2]; dq[35]=0.f;
  dk[32]=cpart[0]; dk[33]=cpart[1]; dk[34]=cpart[2]; dk[35]=0.f;
}

// ---------------- LSH hash values + per-(c,h) hi/lo
__global__ __launch_bounds__(256) void k_hash(const float* __restrict__ q_hat,
        const float* __restrict__ k_hat, const float* __restrict__ alpha,
        float* __restrict__ qh_buf, float* __restrict__ kh_buf,
        unsigned* __restrict__ slots_hi, unsigned* __restrict__ slots_lo){
  int h = blockIdx.y;
  int n = blockIdx.x*256 + threadIdx.x;
  __shared__ float A[DH][NC];
  for (int idx = threadIdx.x; idx < DH*NC; idx += 256)
    A[idx/3][idx%3] = alpha[h*DH*NC + idx];
  __syncthreads();
  float qr[DH], kr[DH];
  const float* qp = q_hat + ((size_t)h*NPTS + n)*DP;
  const float* kp = k_hat + ((size_t)h*NPTS + n)*DP;
  #pragma unroll
  for (int d = 0; d < DH; ++d){ qr[d] = qp[d]; kr[d] = kp[d]; }
  #pragma unroll
  for (int c = 0; c < NC; ++c){
    float qh = 0.f, kh = 0.f;
    #pragma unroll
    for (int d = 0; d < DH; ++d){ qh += qr[d]*A[d][c]; kh += kr[d]*A[d][c]; }
    qh_buf[((size_t)(c*NH + h))*NPTS + n] = qh;
    kh_buf[((size_t)(c*NH + h))*NPTS + n] = kh;
    float hi = fmaxf(qh, kh), lo = fminf(qh, kh);
    #pragma unroll
    for (int off = 32; off; off >>= 1){
      hi = fmaxf(hi, __shfl_xor(hi, off));
      lo = fminf(lo, __shfl_xor(lo, off));
    }
    if ((threadIdx.x & 63) == 0){
      atomicMax(&slots_hi[c*NH + h], fmap(hi));
      atomicMin(&slots_lo[c*NH + h], fmap(lo));
    }
  }
}

// ---------------- build packed sort keys
__global__ __launch_bounds__(256) void k_pack(const float* __restrict__ qh_buf,
        const float* __restrict__ kh_buf, const int* __restrict__ shifts,
        const unsigned* __restrict__ slots_hi, const unsigned* __restrict__ slots_lo,
        ull* __restrict__ packed){
  int seg = blockIdx.y;
  int n = blockIdx.x*256 + threadIdx.x;
  float hs = funmap(slots_hi[seg]) - funmap(slots_lo[seg]);
  size_t idx = (size_t)seg*NPTS + n;
  float sh = (float)shifts[idx] * hs;
  float kq = qh_buf[idx] + sh;
  float kk = kh_buf[idx] + sh;
  packed[(size_t)seg*NPTS + n]          = ((ull)fmap(kq) << 32) | (unsigned)n;
  packed[(size_t)(NSEG + seg)*NPTS + n] = ((ull)fmap(kk) << 32) | (unsigned)n;
}

// ---------------- bitonic sort: LDS chunk kernel (8192 elems, phases k_lo..k_hi, j<=4096)
__global__ __launch_bounds__(1024) void k_sort_local(ull* __restrict__ data,
        unsigned k_lo, unsigned k_hi){
  __shared__ ull ld[8192];     // 64 KB
  int chunk = blockIdx.x;
  size_t base = (size_t)chunk * 8192;
  unsigned segoff = (unsigned)(chunk & 3) * 8192u;  // index within 32768-segment
  for (int idx = threadIdx.x; idx < 8192; idx += 1024) ld[idx] = data[base + idx];
  __syncthreads();
  for (unsigned k = k_lo; k <= k_hi; k <<= 1){
    unsigned j0 = (k >> 1) < 4096u ? (k >> 1) : 4096u;
    for (unsigned j = j0; j > 0; j >>= 1){
      for (unsigned p = threadIdx.x; p < 4096; p += 1024){
        unsigned i  = ((p & ~(j-1)) << 1) | (p & (j-1));
        unsigned x2 = i | j;
        bool up = (((segoff + i) & k) == 0);
        ull a = ld[i], b = ld[x2];
        if ((a > b) == up){ ld[i] = b; ld[x2] = a; }
      }
      __syncthreads();
    }
  }
  for (int idx = threadIdx.x; idx < 8192; idx += 1024) data[base + idx] = ld[idx];
}

// ---------------- bitonic sort: one global compare-exchange pass
__global__ __launch_bounds__(256) void k_sort_global(ull* __restrict__ data,
        unsigned k, unsigned j){
  unsigned t = blockIdx.x*256 + threadIdx.x;       // 48*16384 total
  unsigned seg = t >> 14;
  unsigned p = t & 16383u;
  unsigned i  = ((p & ~(j-1)) << 1) | (p & (j-1));
  unsigned x2 = i | j;
  size_t base = (size_t)seg << 15;
  bool up = ((i & k) == 0);
  ull a = data[base + i], b = data[base + x2];
  if ((a > b) == up){ data[base + i] = b; data[base + x2] = a; }
}

// ---------------- bucketed kernelized attention (MFMA, split-bf16)
// S^T = K.Q^T via mfma_16x16x32_bf16 with hi/lo split; ksq/qsq folded into
// appended dims (35: ksq * 1.0 ; 36: 1.0 * qsq). P -> bf16 -> PV via MFMA.
__global__ __launch_bounds__(256, 2) void k_attn(const float* __restrict__ q_hat,
        const float* __restrict__ k_hat, const float* __restrict__ val,
        const ull* __restrict__ packed, float* __restrict__ o_acc,
        float* __restrict__ logit_acc){
  __shared__ short Khi[128*64];      // [key][dim] swizzled, 16 KB
  __shared__ short Klo[128*64];      // 16 KB
  __shared__ short Vt[32*128];       // [vdim][key] swizzled, 8 KB
  __shared__ short Plds[4*32*128];   // per-wave [q][key] swizzled, 32 KB
  __shared__ float qsqs[128];
  __shared__ unsigned iq_lds[128];

  int t = threadIdx.x;
  int blk = blockIdx.x;
  int seg = blk >> 8;
  int b = blk & 255;
  int h = seg & 7;
  const ull* pq = packed + ((size_t)seg << 15) + (size_t)b*BSZ;
  const ull* pk = packed + ((size_t)(NSEG + seg) << 15) + (size_t)b*BSZ;

  if (t < 128){
    // stage K row t: dims 0..34 data, 35 = ksq, 36 = 1.0, 37..63 = 0
    unsigned ik = (unsigned)(pk[t] & 0xffffffffull);
    const float* kr = k_hat + ((size_t)h*NPTS + ik)*DP;
    float f[36];
    #pragma unroll
    for (int u = 0; u < 9; ++u) *(float4*)&f[u*4] = ((const float4*)kr)[u];
    float ksq = 0.f;
    #pragma unroll
    for (int d = 0; d < 36; ++d) ksq += f[d]*f[d];   // f[35] is 0 pad
    ksq = -0.5f * ksq;
    f[35] = ksq;
    int rowbase = t*64;
    int sw = (t & 7) << 3;
    unsigned* KhiU = (unsigned*)Khi;
    unsigned* KloU = (unsigned*)Klo;
    #pragma unroll
    for (int c = 0; c < 36; c += 2){
      float a = f[c], bb = f[c+1];
      unsigned short ah = f2bf(a), bh = f2bf(bb);
      unsigned short al = f2bf(a - bf2f(ah)), bl = f2bf(bb - bf2f(bh));
      int idx = (rowbase + (c ^ sw)) >> 1;
      KhiU[idx] = (unsigned)ah | ((unsigned)bh << 16);
      KloU[idx] = (unsigned)al | ((unsigned)bl << 16);
    }
    #pragma unroll
    for (int c = 36; c < 64; c += 2){
      int idx = (rowbase + (c ^ sw)) >> 1;
      KhiU[idx] = (c == 36) ? 0x00003f80u : 0u;   // dim36 = 1.0 bf16
      KloU[idx] = 0u;
    }
  } else {
    // stage V^T row + q-row metadata
    int r = t - 128;
    unsigned ik = (unsigned)(pk[r] & 0xffffffffull);
    const float* vr = val + ((size_t)h*NPTS + ik)*DIM;
    float fv[32];
    #pragma unroll
    for (int u = 0; u < 8; ++u) *(float4*)&fv[u*4] = ((const float4*)vr)[u];
    #pragma unroll
    for (int vd = 0; vd < 32; ++vd)
      Vt[vd*128 + (r ^ ((vd&7)<<3))] = (short)f2bf(fv[vd]);
    unsigned iq = (unsigned)(pq[r] & 0xffffffffull);
    iq_lds[r] = iq;
    const float* qr = q_hat + ((size_t)h*NPTS + iq)*DP;
    float qs = 0.f;
    #pragma unroll
    for (int u = 0; u < 9; ++u){
      float4 q4 = ((const float4*)qr)[u];
      qs += q4.x*q4.x + q4.y*q4.y + q4.z*q4.z + q4.w*q4.w;
    }
    qsqs[r] = -0.5f * qs;
  }
  __syncthreads();

  int lane = t & 63;
  int w = t >> 6;
  int l15 = lane & 15, g = lane >> 4;

  // Q B-fragments from global (wave-private rows), dims 35=1.0, 36=qsq
  bf16x8 qhiF[2][2], qloF[2][2];
  unsigned iqa[2];
  #pragma unroll
  for (int qt = 0; qt < 2; ++qt){
    int qrow = 32*w + 16*qt + l15;
    unsigned iq = iq_lds[qrow];
    iqa[qt] = iq;
    const float* qr = q_hat + ((size_t)h*NPTS + iq)*DP;
    float f0[8];
    *(float4*)&f0[0] = *(const float4*)&qr[8*g];
    *(float4*)&f0[4] = *(const float4*)&qr[8*g + 4];
    cvt8(f0, qhiF[qt][0], qloF[qt][0]);
    float f1[8] = {0.f,0.f,0.f,0.f,0.f,0.f,0.f,0.f};
    if (g == 0){
      float4 q4 = *(const float4*)&qr[32];
      f1[0] = q4.x; f1[1] = q4.y; f1[2] = q4.z;
      f1[3] = 1.0f;           // pairs with ksq at dim35
      f1[4] = qsqs[qrow];     // pairs with 1.0 at dim36
    }
    cvt8(f1, qhiF[qt][1], qloF[qt][1]);
  }

  // QK^T (S^T = K.Q^T), hi*hi + lo*hi + hi*lo
  f32x4 acc[8][2];
  #pragma unroll
  for (int kt = 0; kt < 8; ++kt)
    #pragma unroll
    for (int qt = 0; qt < 2; ++qt)
      acc[kt][qt] = (f32x4){0.f,0.f,0.f,0.f};

  #pragma unroll
  for (int kt = 0; kt < 8; ++kt){
    int krow = 16*kt + l15;
    int base = krow*64;
    int sw = (krow & 7) << 3;
    bf16x8 ah0 = *(const bf16x8*)&Khi[base + ((8*g) ^ sw)];
    bf16x8 ah1 = *(const bf16x8*)&Khi[base + ((32 + 8*g) ^ sw)];
    bf16x8 al0 = *(const bf16x8*)&Klo[base + ((8*g) ^ sw)];
    bf16x8 al1 = *(const bf16x8*)&Klo[base + ((32 + 8*g) ^ sw)];
    #pragma unroll
    for (int qt = 0; qt < 2; ++qt){
      f32x4 c = acc[kt][qt];
      c = __builtin_amdgcn_mfma_f32_16x16x32_bf16(ah0, qhiF[qt][0], c, 0, 0, 0);
      c = __builtin_amdgcn_mfma_f32_16x16x32_bf16(ah1, qhiF[qt][1], c, 0, 0, 0);
      c = __builtin_amdgcn_mfma_f32_16x16x32_bf16(al0, qhiF[qt][0], c, 0, 0, 0);
      c = __builtin_amdgcn_mfma_f32_16x16x32_bf16(al1, qhiF[qt][1], c, 0, 0, 0);
      c = __builtin_amdgcn_mfma_f32_16x16x32_bf16(ah0, qloF[qt][0], c, 0, 0, 0);
      c = __builtin_amdgcn_mfma_f32_16x16x32_bf16(ah1, qloF[qt][1], c, 0, 0, 0);
      acc[kt][qt] = c;
    }
  }

  // exp + P -> bf16 -> wave-private LDS stripe; fp32 denom per lane
  float dena[2] = {0.f, 0.f};
  #pragma unroll
  for (int kt = 0; kt < 8; ++kt){
    #pragma unroll
    for (int qt = 0; qt < 2; ++qt){
      f32x4 c = acc[kt][qt];
      float p0 = __expf(fminf(c[0], 0.f));
      float p1 = __expf(fminf(c[1], 0.f));
      float p2 = __expf(fminf(c[2], 0.f));
      float p3 = __expf(fminf(c[3], 0.f));
      dena[qt] += p0 + p1 + p2 + p3;
      int qloc = 16*qt + l15;
      int col = (16*kt + 4*g) ^ ((qloc & 7) << 3);
      uint2 pv;
      pv.x = (unsigned)f2bf(p0) | ((unsigned)f2bf(p1) << 16);
      pv.y = (unsigned)f2bf(p2) | ((unsigned)f2bf(p3) << 16);
      *(uint2*)&Plds[w*4096 + qloc*128 + col] = pv;
    }
  }

  // PV via MFMA: O = P.V  (A = P from stripe, B = V^T rows)
  f32x4 oacc[2][2];
  #pragma unroll
  for (int qt = 0; qt < 2; ++qt)
    #pragma unroll
    for (int nt = 0; nt < 2; ++nt)
      oacc[qt][nt] = (f32x4){0.f,0.f,0.f,0.f};

  #pragma unroll
  for (int ks = 0; ks < 4; ++ks){
    bf16x8 pA[2], vB[2];
    #pragma unroll
    for (int qt = 0; qt < 2; ++qt){
      int qloc = 16*qt + l15;
      pA[qt] = *(const bf16x8*)&Plds[w*4096 + qloc*128 + ((32*ks + 8*g) ^ ((qloc&7)<<3))];
    }
    #pragma unroll
    for (int nt = 0; nt < 2; ++nt){
      int vd = 16*nt + l15;
      vB[nt] = *(const bf16x8*)&Vt[vd*128 + ((32*ks + 8*g) ^ ((vd&7)<<3))];
    }
    #pragma unroll
    for (int qt = 0; qt < 2; ++qt)
      #pragma unroll
      for (int nt = 0; nt < 2; ++nt)
        oacc[qt][nt] = __builtin_amdgcn_mfma_f32_16x16x32_bf16(pA[qt], vB[nt], oacc[qt][nt], 0, 0, 0);
  }

  // denom scatter
  #pragma unroll
  for (int qt = 0; qt < 2; ++qt){
    float d = dena[qt];
    d += __shfl_xor(d, 16);
    d += __shfl_xor(d, 32);
    if (lane < 16) atomicAdd(&logit_acc[(size_t)h*NPTS + iqa[qt]], d + 1e-20f);
  }
  // O scatter
  #pragma unroll
  for (int qt = 0; qt < 2; ++qt){
    #pragma unroll
    for (int nt = 0; nt < 2; ++nt){
      f32x4 c = oacc[qt][nt];
      #pragma unroll
      for (int r = 0; r < 4; ++r){
        int qrow = 32*w + 16*qt + 4*g + r;
        unsigned iq = iq_lds[qrow];
        atomicAdd(&o_acc[((size_t)h*NPTS + iq)*DIM + 16*nt + l15], c[r]);
      }
    }
  }
}

// ---------------- out-proj + residual + LN2 + FF + residual
__global__ __launch_bounds__(256) void k_final(const float* __restrict__ x,
        const float* __restrict__ o_acc, const float* __restrict__ logit_acc,
        const float* __restrict__ out_w, const float* __restrict__ out_b,
        const float* __restrict__ n2w, const float* __restrict__ n2b,
        const float* __restrict__ f1w, const float* __restrict__ f1b,
        const float* __restrict__ f2w, const float* __restrict__ f2b,
        float* __restrict__ out){
  __shared__ float OW[256][32];   // 32 KB
  __shared__ float F1[32][32];
  __shared__ float F2[32][32];
  int tid = threadIdx.x;
  for (int idx = tid; idx < 256*32; idx += 256) OW[idx/32][idx%32] = out_w[idx];
  for (int idx = tid; idx < 1024; idx += 256){
    F1[idx/32][idx%32] = f1w[idx];
    F2[idx/32][idx%32] = f2w[idx];
  }
  __syncthreads();
  int n = blockIdx.x*256 + tid;
  float attn[32];
  #pragma unroll
  for (int j = 0; j < 32; ++j) attn[j] = out_b[j];
  for (int h = 0; h < 8; ++h){
    float inv = 1.f / logit_acc[(size_t)h*NPTS + n];
    const float4* orow = (const float4*)(o_acc + ((size_t)h*NPTS + n)*DIM);
    #pragma unroll
    for (int u = 0; u < 8; ++u){
      float4 ov = orow[u];
      float vals[4] = {ov.x*inv, ov.y*inv, ov.z*inv, ov.w*inv};
      #pragma unroll
      for (int s = 0; s < 4; ++s){
        const float* wrow = &OW[h*32 + u*4 + s][0];
        #pragma unroll
        for (int j = 0; j < 32; ++j) attn[j] += vals[s] * wrow[j];
      }
    }
  }
  const float* xp = x + (size_t)n*DIM;
  float xr[32]; float s = 0.f;
  #pragma unroll
  for (int d = 0; d < 32; ++d){ xr[d] = xp[d] + attn[d]; s += xr[d]; }
  float mu = s * (1.f/32.f);
  float var = 0.f;
  #pragma unroll
  for (int d = 0; d < 32; ++d){ float dx = xr[d]-mu; var += dx*dx; }
  var *= (1.f/32.f);
  float rs = rsqrtf(var + 1e-5f);
  float xn2[32];
  #pragma unroll
  for (int d = 0; d < 32; ++d) xn2[d] = (xr[d]-mu)*rs*n2w[d] + n2b[d];
  float z[32];
  #pragma unroll
  for (int j = 0; j < 32; ++j) z[j] = f1b[j];
  #pragma unroll
  for (int d = 0; d < 32; ++d){
    float xd = xn2[d];
    const float* wrow = &F1[d][0];
    #pragma unroll
    for (int j = 0; j < 32; ++j) z[j] += xd * wrow[j];
  }
  #pragma unroll
  for (int j = 0; j < 32; ++j) z[j] = z[j] / (1.f + __expf(-z[j]));
  float y[32];
  #pragma unroll
  for (int d = 0; d < 32; ++d) y[d] = f2b[d];
  #pragma unroll
  for (int j = 0; j < 32; ++j){
    float zj = z[j];
    const float* wrow = &F2[j][0];
    #pragma unroll
    for (int d = 0; d < 32; ++d) y[d] += zj * wrow[d];
  }
  float* op = out + (size_t)n*DIM;
  #pragma unroll
  for (int d = 0; d < 32; ++d) op[d] = xr[d] + y[d];
}

extern "C" void kernel_launch(void* const* d_in, const int* in_sizes, int n_in,
                              void* d_out, int out_size, void* d_ws, size_t ws_size,
                              hipStream_t stream){
  const float* x      = (const float*)d_in[0];
  const float* coords = (const float*)d_in[1];
  const int*   shifts = (const int*)d_in[2];
  const float* n1w    = (const float*)d_in[3];
  const float* n1b    = (const float*)d_in[4];
  const float* wq     = (const float*)d_in[5];
  const float* wk     = (const float*)d_in[6];
  const float* wv     = (const float*)d_in[7];
  const float* w_rpe  = (const float*)d_in[8];
  const float* alpha  = (const float*)d_in[9];
  const float* out_w  = (const float*)d_in[10];
  const float* out_b  = (const float*)d_in[11];
  const float* n2w    = (const float*)d_in[12];
  const float* n2b    = (const float*)d_in[13];
  const float* f1w    = (const float*)d_in[14];
  const float* f1b    = (const float*)d_in[15];
  const float* f2w    = (const float*)d_in[16];
  const float* f2b    = (const float*)d_in[17];
  float* out = (float*)d_out;

  char* ws = (char*)d_ws;
  size_t off = 0;
  auto alloc = [&](size_t bytes){ size_t o = off; off += (bytes + 255) & ~(size_t)255; return o; };
  float*    qw_sqrt   = (float*)   (ws + alloc(24*4));
  unsigned* slots_hi  = (unsigned*)(ws + alloc(24*4));
  unsigned* slots_lo  = (unsigned*)(ws + alloc(24*4));
  float*    xn        = (float*)   (ws + alloc((size_t)NPTS*DIM*4));
  float*    q_hat     = (float*)   (ws + alloc((size_t)NH*NPTS*DP*4));
  float*    k_hat     = (float*)   (ws + alloc((size_t)NH*NPTS*DP*4));
  float*    val       = (float*)   (ws + alloc((size_t)NH*NPTS*DIM*4));
  float*    qh_buf    = (float*)   (ws + alloc((size_t)NSEG*NPTS*4));
  float*    kh_buf    = (float*)   (ws + alloc((size_t)NSEG*NPTS*4));
  ull*      packed    = (ull*)     (ws + alloc((size_t)2*NSEG*NPTS*8));
  float*    o_acc     = (float*)   (ws + alloc((size_t)NH*NPTS*DIM*4));
  float*    logit_acc = (float*)   (ws + alloc((size_t)NH*NPTS*4));
  if (off > ws_size) return;   // workspace too small -> leave output poisoned

  hipMemsetAsync(o_acc, 0, (size_t)NH*NPTS*DIM*4, stream);
  hipMemsetAsync(logit_acc, 0, (size_t)NH*NPTS*4, stream);

  k_prep<<<1, 256, 0, stream>>>(w_rpe, qw_sqrt, slots_hi, slots_lo);
  k_ln<<<NPTS/256, 256, 0, stream>>>(x, n1w, n1b, xn);
  k_qkv<<<NPTS/32, 256, 0, stream>>>(xn, coords, wq, wk, wv, qw_sqrt, q_hat, k_hat, val);
  k_hash<<<dim3(NPTS/256, NH), 256, 0, stream>>>(q_hat, k_hat, alpha, qh_buf, kh_buf,
                                                 slots_hi, slots_lo);
  k_pack<<<dim3(NPTS/256, NSEG), 256, 0, stream>>>(qh_buf, kh_buf, shifts,
                                                   slots_hi, slots_lo, packed);
  // 48 segments of 32768 -> bitonic
  k_sort_local<<<2*NSEG*4, 1024, 0, stream>>>(packed, 2u, 8192u);
  k_sort_global<<<(2*NSEG*16384)/256, 256, 0, stream>>>(packed, 16384u, 8192u);
  k_sort_local<<<2*NSEG*4, 1024, 0, stream>>>(packed, 16384u, 16384u);
  k_sort_global<<<(2*NSEG*16384)/256, 256, 0, stream>>>(packed, 32768u, 16384u);
  k_sort_global<<<(2*NSEG*16384)/256, 256, 0, stream>>>(packed, 32768u, 8192u);
  k_sort_local<<<2*NSEG*4, 1024, 0, stream>>>(packed, 32768u, 32768u);

  k_attn<<<NSEG*NB, 256, 0, stream>>>(q_hat, k_hat, val, packed, o_acc, logit_acc);
  k_final<<<NPTS/256, 256, 0, stream>>>(x, o_acc, logit_acc, out_w, out_b,
                                        n2w, n2b, f1w, f1b, f2w, f2b, out);
}